// Round 5
// baseline (1636.439 us; speedup 1.0000x reference)
//
#include <hip/hip_runtime.h>

// ---------------- constants ----------------
#define CUTOFF_F     0.35f
#define PI_F         3.14159265358979323846f
#define SQRT3_F      1.7320508075688772f
#define INV_SQRT3_F  0.5773502691896258f
#define INV_SQRT_S_F 0.17677669529663687f   // 1/sqrt(32)
#define INV_SQRT_V_F 0.25f                  // 1/sqrt(16)
#define A_SC_F       0.14433756729740643f   // 1/sqrt(48)

// ws layout (floats): [0..12) M matrix, [16..) node state double buffers
#define OFF_M    0
#define OFF_NODE 16

// M[c][k] = (1/256) * Y[:,c] . dirs[:,k];  Y = [1, sqrt3*dirs]
__global__ void mmat_kernel(const float* __restrict__ dirs, float* __restrict__ wf) {
  int t = threadIdx.x;
  if (t >= 12) return;
  int c = t / 3, k = t - c * 3;
  float acc = 0.f;
  for (int p = 0; p < 256; ++p) {
    float dk = dirs[p * 3 + k];
    acc += (c == 0) ? dk : dirs[p * 3 + (c - 1)] * dk;
  }
  wf[OFF_M + t] = acc * ((c == 0) ? (1.0f / 256.0f) : (SQRT3_F / 256.0f));
}

// s0[n][w] = (x[n,0:3] @ Wins)[w]/sqrt3 ; v0[n][u][k] = x[n,3+k]*Winv[u]
__global__ __launch_bounds__(256) void node_init_kernel(
    const float* __restrict__ x, const float* __restrict__ wins,
    const float* __restrict__ winv,
    float* __restrict__ s0, float* __restrict__ v0, int N)
{
  int t = blockIdx.x * 256 + threadIdx.x;
  int n = t / 80; int slot = t - n * 80;
  if (n >= N) return;
  if (slot < 32) {
    float acc = 0.f;
    #pragma unroll
    for (int d = 0; d < 3; ++d) acc += x[n * 6 + d] * wins[d * 32 + slot];
    s0[n * 32 + slot] = acc * INV_SQRT3_F;
  } else {
    int j = slot - 32; int u = j / 3; int k = j - u * 3;
    v0[n * 48 + j] = x[n * 6 + 3 + k] * winv[u];
  }
}

// self-connection: sn = (sc @ Wsc_s)*inv_s ; vn = (vc x Wsc_v)*inv_v  (full overwrite)
__global__ __launch_bounds__(256) void selfmix_kernel(
    const float* __restrict__ sc, const float* __restrict__ vc,
    float* __restrict__ sn, float* __restrict__ vn,
    const float* __restrict__ wscs, const float* __restrict__ wscv,
    int layer, int N)
{
  int t = blockIdx.x * 256 + threadIdx.x;
  int n = t / 80; int slot = t - n * 80;
  if (n >= N) return;
  if (slot < 32) {
    const float* W = wscs + layer * 1024;
    float acc = 0.f;
    #pragma unroll
    for (int u = 0; u < 32; ++u) acc += sc[n * 32 + u] * W[u * 32 + slot];
    sn[n * 32 + slot] = acc * INV_SQRT_S_F;
  } else {
    int j = slot - 32; int w = j / 3; int k = j - w * 3;
    const float* W = wscv + layer * 256;
    float acc = 0.f;
    #pragma unroll
    for (int u = 0; u < 16; ++u) acc += vc[n * 48 + u * 3 + k] * W[u * 16 + w];
    vn[n * 48 + j] = acc * INV_SQRT_V_F;
  }
}

// ---------------- per-edge kernel: ONE THREAD PER EDGE ----------------
__global__ __launch_bounds__(256, 1) void edge_kernel(
    const int* __restrict__ ei, const float* __restrict__ ed,
    const float* __restrict__ esh,
    const float* __restrict__ sc, const float* __restrict__ vc,
    float* __restrict__ sn, float* __restrict__ vn,
    const float* __restrict__ wr1, const float* __restrict__ br1,
    const float* __restrict__ wr2, const float* __restrict__ br2,
    const float* __restrict__ wpgs, const float* __restrict__ wpgv,
    const float* __restrict__ wlos, const float* __restrict__ wlov,
    int layer, int E, int N)
{
  const int e = blockIdx.x * 256 + threadIdx.x;
  if (e >= E) return;
  int srcn = ei[e];     srcn = (srcn < 0) ? 0 : (srcn >= N ? N - 1 : srcn);
  int dstn = ei[E + e]; dstn = (dstn < 0) ? 0 : (dstn >= N ? N - 1 : dstn);
  const float y0  = esh[e * 4 + 0];
  const float y1x = esh[e * 4 + 1];
  const float y1y = esh[e * 4 + 2];
  const float y1z = esh[e * 4 + 3];

  // ---- hext[33]: h = silu(rbf @ Wr1 + br1), hext[32] = 1 (br2 bias row) ----
  float h[33];
  {
    const float d = ed[e];
    const float inv_w = 12.0f / CUTOFF_F;
    float cut = (d < CUTOFF_F) ? 0.5f * (__cosf(d * (PI_F / CUTOFF_F)) + 1.0f) : 0.0f;
    float rb[6];
    #pragma unroll
    for (int r = 0; r < 6; ++r) {
      float z = (d - 0.07f * (float)r) * inv_w;
      rb[r] = __expf(-0.5f * z * z) * cut;
    }
    const float* W1p = wr1 + layer * 192;
    const float* B1p = br1 + layer * 32;
    #pragma unroll
    for (int j = 0; j < 32; ++j) {
      float z = B1p[j];
      #pragma unroll
      for (int r = 0; r < 6; ++r) z += rb[r] * W1p[r * 32 + j];
      h[j] = z / (1.0f + __expf(-z));   // silu
    }
    h[32] = 1.0f;
  }

  // ---- pass 1: A[w] = sum_u sj[u]*W1[u,w], C[w] = sum_u sj[u]*W3[u,w] ----
  float sj[32];
  #pragma unroll
  for (int u = 0; u < 32; ++u) sj[u] = sc[srcn * 32 + u];
  float A[32], C[16];
  #pragma unroll
  for (int w = 0; w < 32; ++w) A[w] = 0.f;
  #pragma unroll
  for (int w = 0; w < 16; ++w) C[w] = 0.f;
  for (int c = 0; c < 33; ++c) {
    const float hc = h[c];
    const float* row = (c < 32) ? (wr2 + (size_t)(layer * 32 + c) * 2304)
                                : (br2 + (size_t)layer * 2304);
    #pragma unroll
    for (int u = 0; u < 32; ++u) {
      const float p = hc * sj[u];
      #pragma unroll
      for (int w = 0; w < 32; ++w) A[w] += p * row[u * 32 + w];
      #pragma unroll
      for (int w = 0; w < 16; ++w) C[w] += p * row[1536 + u * 16 + w];
    }
  }

  // ---- pass 2: B[w] = sum_u vdot[u]*W2[u,w], D[w,k] = sum_u vj[u,k]*W4[u,w] ----
  float vj[48];
  #pragma unroll
  for (int j = 0; j < 48; ++j) vj[j] = vc[srcn * 48 + j];
  float vdot[16];
  #pragma unroll
  for (int u = 0; u < 16; ++u)
    vdot[u] = vj[u * 3] * y1x + vj[u * 3 + 1] * y1y + vj[u * 3 + 2] * y1z;
  float B[32], D[48];
  #pragma unroll
  for (int w = 0; w < 32; ++w) B[w] = 0.f;
  #pragma unroll
  for (int j = 0; j < 48; ++j) D[j] = 0.f;
  for (int c = 0; c < 33; ++c) {
    const float hc = h[c];
    const float* row = (c < 32) ? (wr2 + (size_t)(layer * 32 + c) * 2304)
                                : (br2 + (size_t)layer * 2304);
    #pragma unroll
    for (int u = 0; u < 16; ++u) {
      const float pb = hc * vdot[u];
      #pragma unroll
      for (int w = 0; w < 32; ++w) B[w] += pb * row[1024 + u * 32 + w];
    }
    #pragma unroll
    for (int u = 0; u < 16; ++u) {
      const float a0 = hc * vj[u * 3 + 0];
      const float a1 = hc * vj[u * 3 + 1];
      const float a2 = hc * vj[u * 3 + 2];
      #pragma unroll
      for (int w = 0; w < 16; ++w) {
        const float t = row[2048 + u * 16 + w];
        D[w * 3 + 0] += a0 * t;
        D[w * 3 + 1] += a1 * t;
        D[w * 3 + 2] += a2 * t;
      }
    }
  }

  // ---- pg ----
  float pgs[48];
  #pragma unroll
  for (int w = 0; w < 48; ++w) pgs[w] = 0.f;
  {
    const float* Wp = wpgs + layer * 1536;
    #pragma unroll
    for (int u = 0; u < 32; ++u) {
      const float ms = A_SC_F * (y0 * A[u] + INV_SQRT3_F * B[u]);
      #pragma unroll
      for (int w = 0; w < 48; ++w) pgs[w] += ms * Wp[u * 48 + w];
    }
  }
  float pgv[48];
  #pragma unroll
  for (int w = 0; w < 48; ++w) pgv[w] = 0.f;
  {
    const float* Wp = wpgv + layer * 256;
    #pragma unroll
    for (int u = 0; u < 16; ++u) {
      const float m0 = A_SC_F * (C[u] * y1x + y0 * D[u * 3 + 0]);
      const float m1 = A_SC_F * (C[u] * y1y + y0 * D[u * 3 + 1]);
      const float m2 = A_SC_F * (C[u] * y1z + y0 * D[u * 3 + 2]);
      #pragma unroll
      for (int w = 0; w < 16; ++w) {
        const float wv = Wp[u * 16 + w];
        pgv[w * 3 + 0] += m0 * wv;
        pgv[w * 3 + 1] += m1 * wv;
        pgv[w * 3 + 2] += m2 * wv;
      }
    }
  }

  // ---- gates ----
  float gs[32];
  #pragma unroll
  for (int u = 0; u < 32; ++u) {
    const float t = pgs[u] * INV_SQRT_S_F;
    gs[u] = t / (1.0f + __expf(-t));
  }
  float gv[48];
  #pragma unroll
  for (int w = 0; w < 16; ++w) {
    const float g = 1.0f / (1.0f + __expf(-pgs[32 + w] * INV_SQRT_S_F));
    #pragma unroll
    for (int k = 0; k < 3; ++k) gv[w * 3 + k] = g * pgv[w * 3 + k] * INV_SQRT_V_F;
  }

  // ---- o = g @ Wlo, scatter to dst ----
  {
    const float* Wp = wlos + layer * 1024;
    float* sdst = sn + (size_t)dstn * 32;
    #pragma unroll
    for (int w = 0; w < 32; ++w) {
      float acc = 0.f;
      #pragma unroll
      for (int u = 0; u < 32; ++u) acc += gs[u] * Wp[u * 32 + w];
      atomicAdd(&sdst[w], acc * INV_SQRT_S_F);
    }
  }
  {
    const float* Wp = wlov + layer * 256;
    float* vdst = vn + (size_t)dstn * 48;
    #pragma unroll
    for (int w = 0; w < 16; ++w) {
      float a0 = 0.f, a1 = 0.f, a2 = 0.f;
      #pragma unroll
      for (int u = 0; u < 16; ++u) {
        const float wv = Wp[u * 16 + w];
        a0 += gv[u * 3 + 0] * wv;
        a1 += gv[u * 3 + 1] * wv;
        a2 += gv[u * 3 + 2] * wv;
      }
      atomicAdd(&vdst[w * 3 + 0], a0 * INV_SQRT_V_F);
      atomicAdd(&vdst[w * 3 + 1], a1 * INV_SQRT_V_F);
      atomicAdd(&vdst[w * 3 + 2], a2 * INV_SQRT_V_F);
    }
  }
}

// out[n,k] = coeffs[n] @ M  (rho @ dirs collapsed analytically) — FP32 OUTPUT
__global__ __launch_bounds__(256) void final_kernel(
    const float* __restrict__ s0, const float* __restrict__ v0,
    const float* __restrict__ wos, const float* __restrict__ wov,
    const float* __restrict__ wf, float* __restrict__ out, int N)
{
  int n = blockIdx.x * 256 + threadIdx.x;
  if (n >= N) return;
  float cs = 0.f;
  #pragma unroll
  for (int u = 0; u < 32; ++u) cs += s0[n * 32 + u] * wos[u];
  cs *= INV_SQRT_S_F;
  float cv0 = 0.f, cv1 = 0.f, cv2 = 0.f;
  #pragma unroll
  for (int u = 0; u < 16; ++u) {
    const float wv = wov[u];
    cv0 += v0[n * 48 + u * 3 + 0] * wv;
    cv1 += v0[n * 48 + u * 3 + 1] * wv;
    cv2 += v0[n * 48 + u * 3 + 2] * wv;
  }
  cv0 *= INV_SQRT_V_F; cv1 *= INV_SQRT_V_F; cv2 *= INV_SQRT_V_F;
  #pragma unroll
  for (int k = 0; k < 3; ++k) {
    float val = cs  * wf[OFF_M + k]
              + cv0 * wf[OFF_M + 3 + k]
              + cv1 * wf[OFF_M + 6 + k]
              + cv2 * wf[OFF_M + 9 + k];
    out[n * 3 + k] = val;
  }
}

extern "C" void kernel_launch(void* const* d_in, const int* in_sizes, int n_in,
                              void* d_out, int out_size, void* d_ws, size_t ws_size,
                              hipStream_t stream)
{
  (void)n_in; (void)out_size; (void)ws_size;
  const float* x    = (const float*)d_in[0];
  const int*   ei   = (const int*)d_in[1];
  const float* ed   = (const float*)d_in[2];
  const float* esh  = (const float*)d_in[3];
  const float* dirs = (const float*)d_in[4];
  const float* wins = (const float*)d_in[5];
  const float* winv = (const float*)d_in[6];
  const float* wscs = (const float*)d_in[7];
  const float* wscv = (const float*)d_in[8];
  const float* wr1  = (const float*)d_in[9];
  const float* br1  = (const float*)d_in[10];
  const float* wr2  = (const float*)d_in[11];
  const float* br2  = (const float*)d_in[12];
  const float* wpgs = (const float*)d_in[13];
  const float* wpgv = (const float*)d_in[14];
  const float* wlos = (const float*)d_in[15];
  const float* wlov = (const float*)d_in[16];
  const float* wos  = (const float*)d_in[17];
  const float* wov  = (const float*)d_in[18];

  const int N = in_sizes[0] / 6;
  const int E = in_sizes[1] / 2;

  float* wf = (float*)d_ws;
  float* s0 = wf + OFF_NODE;
  float* v0 = s0 + (size_t)N * 32;
  float* s1 = v0 + (size_t)N * 48;
  float* v1 = s1 + (size_t)N * 32;

  const int nodeBlocks = (N * 80 + 255) / 256;
  const int edgeBlocks = (E + 255) / 256;
  const int finBlocks  = (N + 255) / 256;

  mmat_kernel<<<1, 64, 0, stream>>>(dirs, wf);
  node_init_kernel<<<nodeBlocks, 256, 0, stream>>>(x, wins, winv, s0, v0, N);

  // layer 0: s0/v0 -> s1/v1
  selfmix_kernel<<<nodeBlocks, 256, 0, stream>>>(s0, v0, s1, v1, wscs, wscv, 0, N);
  edge_kernel<<<edgeBlocks, 256, 0, stream>>>(ei, ed, esh, s0, v0, s1, v1,
      wr1, br1, wr2, br2, wpgs, wpgv, wlos, wlov, 0, E, N);
  // layer 1: s1/v1 -> s0/v0
  selfmix_kernel<<<nodeBlocks, 256, 0, stream>>>(s1, v1, s0, v0, wscs, wscv, 1, N);
  edge_kernel<<<edgeBlocks, 256, 0, stream>>>(ei, ed, esh, s1, v1, s0, v0,
      wr1, br1, wr2, br2, wpgs, wpgv, wlos, wlov, 1, E, N);

  final_kernel<<<finBlocks, 256, 0, stream>>>(s0, v0, wos, wov, wf,
      (float*)d_out, N);
}